// Round 15
// baseline (1089.915 us; speedup 1.0000x reference)
//
#include <hip/hip_runtime.h>
#include <math.h>

// ---------------------------------------------------------------------------
// DynamicPerceiverEncoder forward — r12/r14 base (64x64 bf16 MFMA GEMMs,
// q64 flash, standalone router+scatter) with BK=64 (halved barrier count,
// LDS 32KB -> still ~5 blocks/CU).
// ---------------------------------------------------------------------------

namespace {

typedef unsigned short u16;
constexpr int Dm  = 768;
constexpr int ML  = 256;
constexpr int BB  = 4;
constexpr int NP  = 196;
constexpr int NV  = 49;
constexpr int NE  = 8;
constexpr int FH_ = 1536;
constexpr int NL  = 6;
constexpr int NT  = 1024;

typedef __attribute__((ext_vector_type(8))) short bf16x8;
typedef __attribute__((ext_vector_type(4))) float f32x4;

__device__ __forceinline__ u16 f2bf(float f){
  union { float f; unsigned u; } v; v.f = f;
  unsigned r = v.u + 0x7fffu + ((v.u >> 16) & 1u);
  return (u16)(r >> 16);
}
__device__ __forceinline__ void pack8(const float4& a, const float4& b, bf16x8& w){
  w[0]=(short)f2bf(a.x); w[1]=(short)f2bf(a.y); w[2]=(short)f2bf(a.z); w[3]=(short)f2bf(a.w);
  w[4]=(short)f2bf(b.x); w[5]=(short)f2bf(b.y); w[6]=(short)f2bf(b.z); w[7]=(short)f2bf(b.w);
}
__device__ __forceinline__ void gload16(const void* g, void* l){
  __builtin_amdgcn_global_load_lds(
      (const __attribute__((address_space(1))) unsigned int*)g,
      (__attribute__((address_space(3))) unsigned int*)l, 16, 0, 0);
}

__device__ __forceinline__ float blk_sum(float v, float* sh){
#pragma unroll
  for (int off = 32; off; off >>= 1) v += __shfl_xor(v, off);
  int wid = threadIdx.x >> 6;
  if ((threadIdx.x & 63) == 0) sh[wid] = v;
  __syncthreads();
  v = sh[0] + sh[1] + sh[2] + sh[3];
  __syncthreads();
  return v;
}

// ---------------- merged prologue: argsort | im2col | weight cvt ----------------
__global__ __launch_bounds__(256) void prologue_k(
    const float* __restrict__ noise, int* __restrict__ ids,
    float* __restrict__ out_keep, float* __restrict__ out_mask,
    const float* __restrict__ images, u16* __restrict__ viscol,
    const float* __restrict__ s0, const float* __restrict__ s1,
    const float* __restrict__ s2, const float* __restrict__ s3,
    const float* __restrict__ s4, const float* __restrict__ s5,
    u16* __restrict__ d0, u16* __restrict__ d1, u16* __restrict__ d2,
    u16* __restrict__ d3, u16* __restrict__ d4, u16* __restrict__ d5)
{
  int bx = blockIdx.x, tid = threadIdx.x;
  __shared__ float shv[NP];
  __shared__ int shord[NP];
  if (bx < 4){
    int b = bx;
    if (tid < NP) shv[tid] = noise[b * NP + tid];
    __syncthreads();
    if (tid < NP){
      float x = shv[tid];
      int rank = 0;
      for (int j = 0; j < NP; j++){
        float y = shv[j];
        rank += (y < x) || (y == x && j < tid);
      }
      shord[rank] = tid;
    }
    __syncthreads();
    if (tid < NP){
      int id = shord[tid];
      ids[b * NP + tid] = id;
      if (tid < NV) out_keep[b * NV + tid] = (float)id;
      else          out_mask[b * (NP - NV) + (tid - NV)] = (float)id;
    }
    return;
  }
  if (bx < 200){
    int bv = bx - 4;
    int b = bv / NV, vq = bv % NV;
    if (tid < NP) shv[tid] = noise[b * NP + tid];
    __syncthreads();
    if (tid < NP){
      float x = shv[tid];
      int rank = 0;
      for (int j = 0; j < NP; j++){
        float y = shv[j];
        rank += (y < x) || (y == x && j < tid);
      }
      if (rank == vq) shord[0] = tid;
    }
    __syncthreads();
    int pid = shord[0];
    int ph = pid / 14, pw = pid % 14;
    int kh = tid >> 4, kw = tid & 15;
#pragma unroll
    for (int c = 0; c < 3; c++)
      viscol[(long)bv * Dm + c * 256 + tid] =
        f2bf(images[((b * 3 + c) * 224 + ph * 16 + kh) * 224 + pw * 16 + kw]);
    return;
  }
  const long c0 = 147456, c1 = 589824, c2 = 737280, c3 = 3391488, c4 = 4276224, c5 = 4325376;
  long i = (long)(bx - 200) * 256 + tid;
  long stride = (long)(gridDim.x - 200) * 256;
  for (; i < c5; i += stride){
    const float* s; u16* d; long off;
    if      (i < c0){ s = s0; d = d0; off = i; }
    else if (i < c1){ s = s1; d = d1; off = i - c0; }
    else if (i < c2){ s = s2; d = d2; off = i - c1; }
    else if (i < c3){ s = s3; d = d3; off = i - c2; }
    else if (i < c4){ s = s4; d = d4; off = i - c3; }
    else            { s = s5; d = d5; off = i - c4; }
    float4 v = *(const float4*)(s + off * 4);
    ushort4 o;
    o.x = f2bf(v.x); o.y = f2bf(v.y); o.z = f2bf(v.z); o.w = f2bf(v.w);
    *(ushort4*)(d + off * 4) = o;
  }
}

// ---------------- double-buffered bf16 MFMA GEMM (MTILE x NTILE, BK=KB) ----------------
// A bf16 [M][lda]. B (BT layout, rows=N): bf16 (gload) or f32 (reg-staged cvt).
// Waves 2x2; wave tile (MTILE/2) x (NTILE/2).
template<int MTILE, int NTILE, int KB, bool BF16B, bool MOE, bool GATHER, bool POSTYPE>
__global__ __launch_bounds__(256) void g2_k(
    const u16* __restrict__ A, int lda,
    const void* __restrict__ Bv, int ldb, long bSB,
    const float* __restrict__ bias, long biasE,
    float* __restrict__ Cf, u16* __restrict__ Cb, int ldc,
    int M, int N, int K, int act,
    const int* __restrict__ counts, const int* __restrict__ offsets,
    const int* __restrict__ ptok, int mbPerE,
    const int* __restrict__ ids, const int* __restrict__ type_ids,
    const float* __restrict__ type_emb)
{
  constexpr int AF  = (MTILE * KB) / 2048;   // gload16 per thread for A tile
  constexpr int MF  = MTILE / 32;            // m-frags per wave
  constexpr int BFN = (NTILE * KB) / 2048;   // gload16 per thread for B tile (bf16)
  constexpr int NF2 = NTILE / 32;            // n-frags per wave
  constexpr int TPR = 256 / NTILE;           // threads per B row (f32 path)
  constexpr int BR4 = (NTILE * KB) / 1024;   // float4 regs per thread (f32 path)
  __shared__ __align__(16) short lsa[2][MTILE * KB];
  __shared__ __align__(16) short lsb[2][NTILE * KB];
  int t = threadIdx.x, lane = t & 63, wid = t >> 6;
  int n0 = blockIdx.x * NTILE;
  int m0, cnt = 0, off = 0;
  const u16* B16 = (const u16*)Bv;
  const float* B32 = (const float*)Bv;
  const float* bb = bias;
  if (MOE){
    int e = blockIdx.y / mbPerE, mb = blockIdx.y - e * mbPerE;
    cnt = counts[e]; m0 = mb * MTILE;
    if (m0 >= cnt) return;
    off = offsets[e];
    if (BF16B) B16 += (long)e * bSB; else B32 += (long)e * bSB;
    bb += (long)e * biasE;
  } else {
    m0 = blockIdx.y * MTILE;
  }

  long aoff[AF];
#pragma unroll
  for (int i = 0; i < AF; i++){
    int idx = i * 256 + t, c = idx / MTILE, r = idx % MTILE;
    int gl = m0 + r;
    long row;
    if (MOE) row = (gl < cnt) ? (GATHER ? (long)ptok[off + gl] : (long)(off + gl))
                              : (GATHER ? (long)ptok[off] : (long)off);
    else     row = (gl < M) ? gl : 0;
    aoff[i] = row * (long)lda + c * 8;
  }
  long boff[BFN];
#pragma unroll
  for (int i = 0; i < BFN; i++) boff[i] = 0;
  int bcol = 0, bkh = 0;
  const float* b32p = nullptr;
  if (BF16B){
#pragma unroll
    for (int i = 0; i < BFN; i++){
      int idx = i * 256 + t, c = idx / NTILE, r = idx % NTILE;
      int gc = n0 + r; if (gc >= N) gc = 0;
      boff[i] = (long)gc * ldb + c * 8;
    }
  } else {
    bcol = t / TPR;
    bkh  = (t % TPR) * (KB / TPR);
    int gc = n0 + bcol; if (gc >= N) gc = N - 1;
    b32p = B32 + (long)gc * ldb + bkh;
  }

  float4 br[BR4];
  auto stage = [&](int buf, int k0){
#pragma unroll
    for (int i = 0; i < AF; i++)
      gload16(A + aoff[i] + k0, &lsa[buf][(i * 256 + wid * 64) * 8]);
    if (BF16B){
#pragma unroll
      for (int i = 0; i < BFN; i++)
        gload16(B16 + boff[i] + k0, &lsb[buf][(i * 256 + wid * 64) * 8]);
    } else {
#pragma unroll
      for (int j = 0; j < BR4; j++) br[j] = *(const float4*)(b32p + k0 + j * 4);
    }
  };
  auto bwrite = [&](int buf){
    if (!BF16B){
#pragma unroll
      for (int p = 0; p < BR4 / 2; p++){
        bf16x8 w;
        pack8(br[2 * p], br[2 * p + 1], w);
        int c = (bkh >> 3) + p;
        *(bf16x8*)&lsb[buf][(c * NTILE + bcol) * 8] = w;
      }
    }
  };

  f32x4 acc[MF][NF2];
#pragma unroll
  for (int m = 0; m < MF; m++)
#pragma unroll
    for (int n = 0; n < NF2; n++) acc[m][n] = (f32x4){0.f,0.f,0.f,0.f};

  int T = K / KB;
  stage(0, 0);
  bwrite(0);
  __syncthreads();

  int wr = wid >> 1, wc = wid & 1, fr = lane & 15, lk = lane >> 4;
  for (int tt = 0; tt < T; tt++){
    int cur = tt & 1, nxt = cur ^ 1;
    if (tt + 1 < T) stage(nxt, (tt + 1) * KB);
#pragma unroll
    for (int kk = 0; kk < KB / 32; kk++){
      bf16x8 av[MF], bv[NF2];
#pragma unroll
      for (int m = 0; m < MF; m++)
        av[m] = *(const bf16x8*)&lsa[cur][((kk * 4 + lk) * MTILE + wr * (MTILE / 2) + m * 16 + fr) * 8];
#pragma unroll
      for (int n = 0; n < NF2; n++)
        bv[n] = *(const bf16x8*)&lsb[cur][((kk * 4 + lk) * NTILE + wc * (NTILE / 2) + n * 16 + fr) * 8];
#pragma unroll
      for (int m = 0; m < MF; m++)
#pragma unroll
        for (int n = 0; n < NF2; n++)
          acc[m][n] = __builtin_amdgcn_mfma_f32_16x16x32_bf16(av[m], bv[n], acc[m][n], 0, 0, 0);
    }
    if (tt + 1 < T) bwrite(nxt);
    __syncthreads();
  }

#pragma unroll
  for (int m = 0; m < MF; m++)
#pragma unroll
  for (int i = 0; i < 4; i++){
    int rl = m0 + wr * (MTILE / 2) + m * 16 + lk * 4 + i;
    bool ok = MOE ? (rl < cnt) : (rl < M);
    if (!ok) continue;
    long grow = MOE ? (long)(off + rl) : (long)rl;
    int pph = 0, ppw = 0, pty = 0;
    if (POSTYPE){
      int pb = rl / NV;
      int pid = ids[pb * NP + rl % NV];
      pph = pid / 14; ppw = pid % 14;
      pty = type_ids[pb];
    }
#pragma unroll
    for (int n = 0; n < NF2; n++){
      int col = n0 + wc * (NTILE / 2) + n * 16 + fr;
      if (col >= N) continue;
      float v = acc[m][n][i] + bb[col];
      if (act) v = 0.5f * v * (1.0f + erff(v * 0.70710678118654752f));
      if (POSTYPE){
        int q = col % 192, sect = col / 192;
        float omega = powf(10000.0f, -(float)q / 192.0f);
        float arg = (sect < 2 ? (float)ppw : (float)pph) * omega;
        float pos = ((sect & 1) == 0) ? sinf(arg) : cosf(arg);
        v += pos + type_emb[(long)pty * Dm + col];
      }
      if (Cf) Cf[grow * (long)ldc + col] = v;
      if (Cb) Cb[grow * (long)ldc + col] = f2bf(v);
    }
  }
}

// ---------------- fused flash attention, q-tile 64 ----------------
template<int KVCAP>
__global__ __launch_bounds__(256) void flash_k(
    const u16* __restrict__ Qp, int ldq, int qBatchRows,
    const u16* __restrict__ Kp, int ldk,
    const u16* __restrict__ Vp, int ldv, int kvBatchRows,
    int qCol0, int kCol0, int vCol0,
    int kvLen, u16* __restrict__ Ob)
{
  constexpr int NF   = KVCAP / 16;
  constexpr int HALF = (KVCAP > 128) ? 128 : KVCAP;
  constexpr int NHF  = KVCAP / HALF;

  __shared__ __align__(16) char sm[49152];
  short* smQ  = (short*)sm;
  short* smK0 = (short*)(sm + 12288);
  short* smK1 = (short*)(sm + 12288 + 4 * KVCAP * 16);
  short* smP  = (short*)sm;
  short* smVT = (short*)(sm + 64 * HALF * 2);

  int t = threadIdx.x, lane = t & 63, wid = t >> 6;
  int fr = lane & 15, lk = lane >> 4;
  int qt = blockIdx.x, z = blockIdx.y, b = z >> 3, h = z & 7;
  int qRow0 = b * qBatchRows + qt * 64;
  int kvRow0 = b * kvBatchRows;
  int oRow0 = b * 256 + qt * 64;
  int qCol = qCol0 + h * 96, kCol = kCol0 + h * 96, vCol = vCol0 + h * 96;
  int wq0 = wid * 16;

#pragma unroll
  for (int i = 0; i < 3; i++){
    int idx = i * 256 + t, c = idx >> 6, r = idx & 63;
    *(bf16x8*)&smQ[idx * 8] = *(const bf16x8*)&Qp[(long)(qRow0 + r) * ldq + qCol + c * 8];
  }
  auto stageK = [&](int k0c, short* dst){
#pragma unroll
    for (int i = 0; i < (4 * KVCAP) / 256; i++){
      int idx = i * 256 + t, c = idx / KVCAP, col = idx % KVCAP;
      int kv = col < kvLen ? col : kvLen - 1;
      *(bf16x8*)&dst[idx * 8] =
        *(const bf16x8*)&Kp[(long)(kvRow0 + kv) * ldk + kCol + (k0c * 4 + c) * 8];
    }
  };
  stageK(0, smK0);
  __syncthreads();

  f32x4 acc[NF];
#pragma unroll
  for (int n = 0; n < NF; n++) acc[n] = (f32x4){0.f,0.f,0.f,0.f};

  for (int k0c = 0; k0c < 3; k0c++){
    short* curK = (k0c & 1) ? smK1 : smK0;
    if (k0c < 2) stageK(k0c + 1, (k0c & 1) ? smK0 : smK1);
    bf16x8 av = *(const bf16x8*)&smQ[((k0c * 4 + lk) * 64 + wq0 + fr) * 8];
#pragma unroll
    for (int n = 0; n < NF; n++){
      bf16x8 bv = *(const bf16x8*)&curK[(lk * KVCAP + n * 16 + fr) * 8];
      acc[n] = __builtin_amdgcn_mfma_f32_16x16x32_bf16(av, bv, acc[n], 0, 0, 0);
    }
    __syncthreads();
  }

  const float scl = 0.10206207261596577f;   // 1/sqrt(96)
  float rinv[4];
#pragma unroll
  for (int i = 0; i < 4; i++){
    float mx = -3e38f;
#pragma unroll
    for (int n = 0; n < NF; n++){
      float v = acc[n][i] * scl;
      if (n * 16 + fr >= kvLen) v = -3e38f;
      acc[n][i] = v;
      mx = fmaxf(mx, v);
    }
#pragma unroll
    for (int s = 1; s < 16; s <<= 1) mx = fmaxf(mx, __shfl_xor(mx, s));
    float sum = 0.f;
#pragma unroll
    for (int n = 0; n < NF; n++){
      float p = __expf(acc[n][i] - mx);
      acc[n][i] = p;
      sum += p;
    }
#pragma unroll
    for (int s = 1; s < 16; s <<= 1) sum += __shfl_xor(sum, s);
    rinv[i] = 1.0f / sum;
  }

  f32x4 acco[6];
#pragma unroll
  for (int n = 0; n < 6; n++) acco[n] = (f32x4){0.f,0.f,0.f,0.f};

  for (int hf = 0; hf < NHF; hf++){
    if (hf) __syncthreads();
#pragma unroll
    for (int np = 0; np < HALF / 16; np++){
      int n = hf * (HALF / 16) + np;
#pragma unroll
      for (int i = 0; i < 4; i++){
        int row = wq0 + lk * 4 + i;
        int cl = np * 16 + fr;
        smP[((cl >> 3) * 64 + row) * 8 + (cl & 7)] = (short)f2bf(acc[n][i]);
      }
    }
    constexpr int G = (HALF * 96 / 8) / 256;
#pragma unroll
    for (int g = 0; g < G; g++){
      int flat = g * 256 + t;
      int kvl = flat / 12, dblk = (flat % 12) * 8;
      int kvg = hf * HALF + kvl;
      int kva = kvg < kvLen ? kvg : kvLen - 1;
      bf16x8 v = *(const bf16x8*)&Vp[(long)(kvRow0 + kva) * ldv + vCol + dblk];
      bool zz = kvg >= kvLen;
#pragma unroll
      for (int j = 0; j < 8; j++)
        smVT[((kvl >> 3) * 96 + dblk + j) * 8 + (kvl & 7)] = zz ? (short)0 : v[j];
    }
    __syncthreads();
#pragma unroll
    for (int kk = 0; kk < HALF / 32; kk++){
      bf16x8 pa = *(const bf16x8*)&smP[((kk * 4 + lk) * 64 + wq0 + fr) * 8];
#pragma unroll
      for (int n = 0; n < 6; n++){
        bf16x8 bv = *(const bf16x8*)&smVT[((kk * 4 + lk) * 96 + n * 16 + fr) * 8];
        acco[n] = __builtin_amdgcn_mfma_f32_16x16x32_bf16(pa, bv, acco[n], 0, 0, 0);
      }
    }
  }

#pragma unroll
  for (int n = 0; n < 6; n++)
#pragma unroll
  for (int i = 0; i < 4; i++){
    int row = oRow0 + wq0 + lk * 4 + i;
    Ob[(long)row * 768 + h * 96 + n * 16 + fr] = f2bf(acco[n][i] * rinv[i]);
  }
}

// ---------------- add residual + LN (dual output) ----------------
__global__ __launch_bounds__(256) void add_ln_k(
    const float* __restrict__ X, const float* __restrict__ R, int rMod,
    const float* __restrict__ w, const float* __restrict__ b,
    float* __restrict__ outf, u16* __restrict__ outb)
{
  int row = blockIdx.x;
  int rrow = rMod ? (row % rMod) : row;
  __shared__ float sh[4];
  float x[3];
#pragma unroll
  for (int i = 0; i < 3; i++){
    int d = threadIdx.x + (i << 8);
    x[i] = X[(long)row * Dm + d] + R[(long)rrow * Dm + d];
  }
  float s = blk_sum(x[0] + x[1] + x[2], sh);
  float mean = s * (1.0f / 768.0f);
  float vs = 0.f;
#pragma unroll
  for (int i = 0; i < 3; i++){ float t = x[i] - mean; vs += t * t; }
  vs = blk_sum(vs, sh);
  float rstd = rsqrtf(vs * (1.0f / 768.0f) + 1e-5f);
#pragma unroll
  for (int i = 0; i < 3; i++){
    int d = threadIdx.x + (i << 8);
    float o = (x[i] - mean) * rstd * w[d] + b[d];
    outf[(long)row * Dm + d] = o;
    if (outb) outb[(long)row * Dm + d] = f2bf(o);
  }
}

// ---------------- MoE router ----------------
__global__ __launch_bounds__(256) void router_k(
    const float* __restrict__ lat, const float* __restrict__ rw, const float* __restrict__ rb,
    int* __restrict__ top_idx, float* __restrict__ top_w)
{
  int t = blockIdx.x, tid = threadIdx.x;
  int e = tid >> 5, lane = tid & 31;
  const float* x = lat + (long)t * Dm;
  const float* w = rw + (long)e * Dm;
  float s = 0.f;
  for (int j = 0; j < 24; j++){ int d = lane + 32 * j; s += x[d] * w[d]; }
#pragma unroll
  for (int off = 16; off; off >>= 1) s += __shfl_xor(s, off);
  __shared__ float lg[NE];
  if (lane == 0) lg[e] = s + rb[e];
  __syncthreads();
  if (tid == 0){
    float m = -1e30f;
    for (int i = 0; i < NE; i++) m = fmaxf(m, lg[i]);
    float p[NE]; float se = 0.f;
    for (int i = 0; i < NE; i++){ p[i] = __expf(lg[i] - m); se += p[i]; }
    float inv = 1.0f / se;
    int i0 = 0, i1 = -1; float v0 = -1.f, v1 = -1.f;
    for (int i = 0; i < NE; i++){
      float pi = p[i] * inv;
      if (pi > v0){ v1 = v0; i1 = i0; v0 = pi; i0 = i; }
      else if (pi > v1){ v1 = pi; i1 = i; }
    }
    float w0 = 1.0f / (1.0f + __expf(v1 - v0));
    top_idx[2 * t] = i0; top_idx[2 * t + 1] = i1;
    top_w[2 * t] = w0;   top_w[2 * t + 1] = 1.0f - w0;
  }
}

// ---------------- group token-expert pairs ----------------
__global__ __launch_bounds__(256) void scatter_k(
    const int* __restrict__ top_idx, int* __restrict__ counts, int* __restrict__ offsets,
    int* __restrict__ ptok, int* __restrict__ posmap)
{
  __shared__ int cnt[NE], cur[NE];
  int tid = threadIdx.x;
  if (tid < NE) cnt[tid] = 0;
  __syncthreads();
  for (int t = tid; t < NT; t += 256){
    atomicAdd(&cnt[top_idx[2 * t]], 1);
    atomicAdd(&cnt[top_idx[2 * t + 1]], 1);
  }
  __syncthreads();
  if (tid == 0){
    int o = 0;
    for (int e = 0; e < NE; e++){ offsets[e] = o; cur[e] = o; counts[e] = cnt[e]; o += cnt[e]; }
  }
  __syncthreads();
  for (int t = tid; t < NT; t += 256){
#pragma unroll
    for (int sidx = 0; sidx < 2; sidx++){
      int e = top_idx[2 * t + sidx];
      int pos = atomicAdd(&cur[e], 1);
      ptok[pos] = t;
      posmap[2 * t + sidx] = pos;
    }
  }
}

// ---------------- MoE combine + residual + LN ----------------
__global__ __launch_bounds__(256) void moe_combine_ln_k(
    const float* __restrict__ OBuf, const int* __restrict__ posmap, const float* __restrict__ topw,
    const float* __restrict__ latin, const float* __restrict__ w, const float* __restrict__ b,
    float* __restrict__ outf, u16* __restrict__ outb)
{
  int t = blockIdx.x;
  int p0 = posmap[2 * t], p1 = posmap[2 * t + 1];
  float w0 = topw[2 * t], w1 = topw[2 * t + 1];
  __shared__ float sh[4];
  float x[3];
#pragma unroll
  for (int i = 0; i < 3; i++){
    int d = threadIdx.x + (i << 8);
    x[i] = w0 * OBuf[(long)p0 * Dm + d] + w1 * OBuf[(long)p1 * Dm + d] + latin[(long)t * Dm + d];
  }
  float s = blk_sum(x[0] + x[1] + x[2], sh);
  float mean = s * (1.0f / 768.0f);
  float vs = 0.f;
#pragma unroll
  for (int i = 0; i < 3; i++){ float tt = x[i] - mean; vs += tt * tt; }
  vs = blk_sum(vs, sh);
  float rstd = rsqrtf(vs * (1.0f / 768.0f) + 1e-5f);
#pragma unroll
  for (int i = 0; i < 3; i++){
    int d = threadIdx.x + (i << 8);
    float o = (x[i] - mean) * rstd * w[d] + b[d];
    outf[(long)t * Dm + d] = o;
    if (outb) outb[(long)t * Dm + d] = f2bf(o);
  }
}

} // namespace

extern "C" void kernel_launch(void* const* d_in, const int* in_sizes, int n_in,
                              void* d_out, int out_size, void* d_ws, size_t ws_size,
                              hipStream_t stream)
{
  (void)in_sizes; (void)n_in; (void)out_size; (void)ws_size;
  const float* images    = (const float*)d_in[0];
  const int*   type_ids  = (const int*)d_in[1];
  const float* noise     = (const float*)d_in[2];
  const float* conv_w    = (const float*)d_in[3];
  const float* conv_b    = (const float*)d_in[4];
  const float* latents   = (const float*)d_in[5];
  const float* type_emb  = (const float*)d_in[6];
  const float* ca_in_w   = (const float*)d_in[7];
  const float* ca_in_b   = (const float*)d_in[8];
  const float* ca_out_w  = (const float*)d_in[9];
  const float* ca_out_b  = (const float*)d_in[10];
  const float* ca_ln_w   = (const float*)d_in[11];
  const float* ca_ln_b   = (const float*)d_in[12];
  const float* blk_in_w  = (const float*)d_in[13];
  const float* blk_in_b  = (const float*)d_in[14];
  const float* blk_out_w = (const float*)d_in[15];
  const float* blk_out_b = (const float*)d_in[16];
  const float* blk_ln1_w = (const float*)d_in[17];
  const float* blk_ln1_b = (const float*)d_in[18];
  const float* blk_ln2_w = (const float*)d_in[19];
  const float* blk_ln2_b = (const float*)d_in[20];
  const float* router_w  = (const float*)d_in[21];
  const float* router_b  = (const float*)d_in[22];
  const float* e_w1      = (const float*)d_in[23];
  const float* e_b1      = (const float*)d_in[24];
  const float* e_w2      = (const float*)d_in[25];
  const float* e_b2      = (const float*)d_in[26];

  char* W = (char*)d_ws;
  float* lat   = (float*)(W + 0);              // 3,145,728
  float* tmp   = (float*)(W + 3145728);        // 3,145,728
  float* obuf  = (float*)(W + 6291456);        // 6,291,456
  float* topw  = (float*)(W + 13185024);
  int*   ids      = (int*)(W + 13193216);
  int*   top_idx  = (int*)(W + 13197312);
  int*   posmap   = (int*)(W + 13205504);
  int*   ptok     = (int*)(W + 13213696);
  int*   counts   = (int*)(W + 13221888);
  int*   offsets  = (int*)(W + 13221952);
  u16* lat_bf    = (u16*)(W + 13258752);       // 1,572,864
  u16* ao_bf     = (u16*)(W + 14831616);       // 1,572,864
  u16* qkv_bf    = (u16*)(W + 16404480);       // 4,718,592
  u16* h_bf      = (u16*)(W + 21123072);       // 6,291,456
  u16* viscol_bf = (u16*)(W + 27414528);       //   301,056
  u16* vis_bf    = (u16*)(W + 27715584);       //   301,056
  u16* qq_bf     = (u16*)(W + 28016640);       //   393,216
  u16* kkvv_bf   = (u16*)(W + 28409856);       //   602,112
  u16* lat0_bf   = (u16*)(W + 29011968);       //   393,216
  u16* convw_bf  = (u16*)(W + 29405184);       // 1,179,648
  u16* caw_bf    = (u16*)(W + 30584832);       // 3,538,944
  u16* caow_bf   = (u16*)(W + 34123776);       // 1,179,648
  u16* blkin_bf  = (u16*)(W + 35303424);       // 21,233,664
  u16* blkout_bf = (u16*)(W + 56537088);       // 7,077,888

  float* out      = (float*)d_out;
  float* out_lat  = out;
  float* out_keep = out + (long)NT * Dm;
  float* out_mask = out_keep + BB * NV;

  dim3 blk(256);

  // ---- merged prologue: argsort + im2col + weight cvt ----
  prologue_k<<<2248, blk, 0, stream>>>(
      noise, ids, out_keep, out_mask, images, viscol_bf,
      conv_w, ca_in_w, ca_out_w, blk_in_w, blk_out_w, latents,
      convw_bf, caw_bf, caow_bf, blkin_bf, blkout_bf, lat0_bf);

  // ---- conv GEMM with fused pos+type epilogue ----
  g2_k<64,64,64,true,false,false,true><<<dim3(12, 4), blk, 0, stream>>>(
      viscol_bf, Dm, convw_bf, Dm, 0, conv_b, 0,
      nullptr, vis_bf, Dm, BB * NV, Dm, Dm, 0,
      nullptr, nullptr, nullptr, 1, ids, type_ids, type_emb);

  // ---- cross attention ----
  g2_k<64,64,64,true,false,false,false><<<dim3(12, 4), blk, 0, stream>>>(
      lat0_bf, Dm, caw_bf, Dm, 0, ca_in_b, 0,
      nullptr, qq_bf, Dm, ML, Dm, Dm, 0,
      nullptr, nullptr, nullptr, 1, nullptr, nullptr, nullptr);
  g2_k<64,64,64,true,false,false,false><<<dim3(24, 4), blk, 0, stream>>>(
      vis_bf, Dm, caw_bf + 768 * 768, Dm, 0, ca_in_b + 768, 0,
      nullptr, kkvv_bf, 1536, BB * NV, 1536, Dm, 0,
      nullptr, nullptr, nullptr, 1, nullptr, nullptr, nullptr);
  flash_k<64><<<dim3(4, 32), blk, 0, stream>>>(
      qq_bf, Dm, 0, kkvv_bf, 1536, kkvv_bf, 1536, NV, 0, 0, 768, NV, ao_bf);
  g2_k<64,64,64,true,false,false,false><<<dim3(12, 16), blk, 0, stream>>>(
      ao_bf, Dm, caow_bf, Dm, 0, ca_out_b, 0,
      tmp, nullptr, Dm, NT, Dm, Dm, 0,
      nullptr, nullptr, nullptr, 1, nullptr, nullptr, nullptr);
  add_ln_k<<<NT, blk, 0, stream>>>(tmp, latents, ML, ca_ln_w, ca_ln_b, lat, lat_bf);

  // ---- transformer blocks ----
  for (int l = 0; l < NL; l++){
    g2_k<64,64,64,true,false,false,false><<<dim3(36, 16), blk, 0, stream>>>(
        lat_bf, Dm, blkin_bf + (long)l * 2304 * 768, Dm, 0, blk_in_b + (long)l * 2304, 0,
        nullptr, qkv_bf, 2304, NT, 2304, Dm, 0,
        nullptr, nullptr, nullptr, 1, nullptr, nullptr, nullptr);
    flash_k<256><<<dim3(4, 32), blk, 0, stream>>>(
        qkv_bf, 2304, ML, qkv_bf, 2304, qkv_bf, 2304, ML, 0, 768, 1536, ML, ao_bf);
    g2_k<64,64,64,true,false,false,false><<<dim3(12, 16), blk, 0, stream>>>(
        ao_bf, Dm, blkout_bf + (long)l * 768 * 768, Dm, 0, blk_out_b + (long)l * 768, 0,
        tmp, nullptr, Dm, NT, Dm, Dm, 0,
        nullptr, nullptr, nullptr, 1, nullptr, nullptr, nullptr);
    add_ln_k<<<NT, blk, 0, stream>>>(tmp, lat, 0,
        blk_ln1_w + (long)l * 768, blk_ln1_b + (long)l * 768, lat, lat_bf);
    router_k<<<NT, blk, 0, stream>>>(lat, router_w + (long)l * NE * Dm,
                                     router_b + (long)l * NE, top_idx, topw);
    scatter_k<<<1, blk, 0, stream>>>(top_idx, counts, offsets, ptok, posmap);
    g2_k<64,64,64,false,true,true,false><<<dim3(24, 128), blk, 0, stream>>>(
        lat_bf, Dm, e_w1 + (long)l * NE * FH_ * Dm, Dm, (long)FH_ * Dm,
        e_b1 + (long)l * NE * FH_, FH_,
        nullptr, h_bf, FH_, 0, FH_, Dm, 1,
        counts, offsets, ptok, 16, nullptr, nullptr, nullptr);
    g2_k<64,64,64,false,true,false,false><<<dim3(12, 128), blk, 0, stream>>>(
        h_bf, FH_, e_w2 + (long)l * NE * Dm * FH_, FH_, (long)Dm * FH_,
        e_b2 + (long)l * NE * Dm, Dm,
        obuf, nullptr, Dm, 0, Dm, FH_, 0,
        counts, offsets, ptok, 16, nullptr, nullptr, nullptr);
    moe_combine_ln_k<<<NT, blk, 0, stream>>>(obuf, posmap, topw, lat,
        blk_ln2_w + (long)l * 768, blk_ln2_b + (long)l * 768,
        (l == NL - 1) ? out_lat : lat, (l == NL - 1) ? nullptr : lat_bf);
  }
}

// Round 16
// 1063.396 us; speedup vs baseline: 1.0249x; 1.0249x over previous
//
#include <hip/hip_runtime.h>
#include <math.h>

// ---------------------------------------------------------------------------
// DynamicPerceiverEncoder forward — FINAL: r12/r14 configuration (1065 us).
// 64x64 bf16 MFMA BK=32 dbuf GEMMs everywhere (grid-parallelism maximized),
// q64 flash attention, standalone router + 1-block scatter, linear MoE grids.
// ---------------------------------------------------------------------------

namespace {

typedef unsigned short u16;
constexpr int Dm  = 768;
constexpr int ML  = 256;
constexpr int BB  = 4;
constexpr int NP  = 196;
constexpr int NV  = 49;
constexpr int NE  = 8;
constexpr int FH_ = 1536;
constexpr int NL  = 6;
constexpr int NT  = 1024;

typedef __attribute__((ext_vector_type(8))) short bf16x8;
typedef __attribute__((ext_vector_type(4))) float f32x4;

__device__ __forceinline__ u16 f2bf(float f){
  union { float f; unsigned u; } v; v.f = f;
  unsigned r = v.u + 0x7fffu + ((v.u >> 16) & 1u);
  return (u16)(r >> 16);
}
__device__ __forceinline__ void pack8(const float4& a, const float4& b, bf16x8& w){
  w[0]=(short)f2bf(a.x); w[1]=(short)f2bf(a.y); w[2]=(short)f2bf(a.z); w[3]=(short)f2bf(a.w);
  w[4]=(short)f2bf(b.x); w[5]=(short)f2bf(b.y); w[6]=(short)f2bf(b.z); w[7]=(short)f2bf(b.w);
}
__device__ __forceinline__ void gload16(const void* g, void* l){
  __builtin_amdgcn_global_load_lds(
      (const __attribute__((address_space(1))) unsigned int*)g,
      (__attribute__((address_space(3))) unsigned int*)l, 16, 0, 0);
}

__device__ __forceinline__ float blk_sum(float v, float* sh){
#pragma unroll
  for (int off = 32; off; off >>= 1) v += __shfl_xor(v, off);
  int wid = threadIdx.x >> 6;
  if ((threadIdx.x & 63) == 0) sh[wid] = v;
  __syncthreads();
  v = sh[0] + sh[1] + sh[2] + sh[3];
  __syncthreads();
  return v;
}

// ---------------- merged prologue: argsort | im2col | weight cvt ----------------
__global__ __launch_bounds__(256) void prologue_k(
    const float* __restrict__ noise, int* __restrict__ ids,
    float* __restrict__ out_keep, float* __restrict__ out_mask,
    const float* __restrict__ images, u16* __restrict__ viscol,
    const float* __restrict__ s0, const float* __restrict__ s1,
    const float* __restrict__ s2, const float* __restrict__ s3,
    const float* __restrict__ s4, const float* __restrict__ s5,
    u16* __restrict__ d0, u16* __restrict__ d1, u16* __restrict__ d2,
    u16* __restrict__ d3, u16* __restrict__ d4, u16* __restrict__ d5)
{
  int bx = blockIdx.x, tid = threadIdx.x;
  __shared__ float shv[NP];
  __shared__ int shord[NP];
  if (bx < 4){
    int b = bx;
    if (tid < NP) shv[tid] = noise[b * NP + tid];
    __syncthreads();
    if (tid < NP){
      float x = shv[tid];
      int rank = 0;
      for (int j = 0; j < NP; j++){
        float y = shv[j];
        rank += (y < x) || (y == x && j < tid);
      }
      shord[rank] = tid;
    }
    __syncthreads();
    if (tid < NP){
      int id = shord[tid];
      ids[b * NP + tid] = id;
      if (tid < NV) out_keep[b * NV + tid] = (float)id;
      else          out_mask[b * (NP - NV) + (tid - NV)] = (float)id;
    }
    return;
  }
  if (bx < 200){
    int bv = bx - 4;
    int b = bv / NV, vq = bv % NV;
    if (tid < NP) shv[tid] = noise[b * NP + tid];
    __syncthreads();
    if (tid < NP){
      float x = shv[tid];
      int rank = 0;
      for (int j = 0; j < NP; j++){
        float y = shv[j];
        rank += (y < x) || (y == x && j < tid);
      }
      if (rank == vq) shord[0] = tid;
    }
    __syncthreads();
    int pid = shord[0];
    int ph = pid / 14, pw = pid % 14;
    int kh = tid >> 4, kw = tid & 15;
#pragma unroll
    for (int c = 0; c < 3; c++)
      viscol[(long)bv * Dm + c * 256 + tid] =
        f2bf(images[((b * 3 + c) * 224 + ph * 16 + kh) * 224 + pw * 16 + kw]);
    return;
  }
  const long c0 = 147456, c1 = 589824, c2 = 737280, c3 = 3391488, c4 = 4276224, c5 = 4325376;
  long i = (long)(bx - 200) * 256 + tid;
  long stride = (long)(gridDim.x - 200) * 256;
  for (; i < c5; i += stride){
    const float* s; u16* d; long off;
    if      (i < c0){ s = s0; d = d0; off = i; }
    else if (i < c1){ s = s1; d = d1; off = i - c0; }
    else if (i < c2){ s = s2; d = d2; off = i - c1; }
    else if (i < c3){ s = s3; d = d3; off = i - c2; }
    else if (i < c4){ s = s4; d = d4; off = i - c3; }
    else            { s = s5; d = d5; off = i - c4; }
    float4 v = *(const float4*)(s + off * 4);
    ushort4 o;
    o.x = f2bf(v.x); o.y = f2bf(v.y); o.z = f2bf(v.z); o.w = f2bf(v.w);
    *(ushort4*)(d + off * 4) = o;
  }
}

// ---------------- double-buffered bf16 MFMA GEMM (MTILE x NTILE, BK=32) ----------------
// A bf16 [M][lda]. B (BT layout, rows=N): bf16 (gload) or f32 (reg-staged cvt).
// Waves 2x2; wave tile (MTILE/2) x (NTILE/2).
template<int MTILE, int NTILE, bool BF16B, bool MOE, bool GATHER, bool POSTYPE>
__global__ __launch_bounds__(256) void g2_k(
    const u16* __restrict__ A, int lda,
    const void* __restrict__ Bv, int ldb, long bSB,
    const float* __restrict__ bias, long biasE,
    float* __restrict__ Cf, u16* __restrict__ Cb, int ldc,
    int M, int N, int K, int act,
    const int* __restrict__ counts, const int* __restrict__ offsets,
    const int* __restrict__ ptok, int mbPerE,
    const int* __restrict__ ids, const int* __restrict__ type_ids,
    const float* __restrict__ type_emb)
{
  constexpr int AF  = MTILE / 64;    // gload16 per thread for A tile
  constexpr int MF  = MTILE / 32;    // m-frags per wave
  constexpr int BFN = NTILE / 64;    // gload16 per thread for B tile (bf16)
  constexpr int NF2 = NTILE / 32;    // n-frags per wave
  constexpr int BR  = (NTILE == 128) ? 4 : 2;  // float4 regs for f32-B path
  __shared__ __align__(16) short lsa[2][MTILE * 32];
  __shared__ __align__(16) short lsb[2][NTILE * 32];
  int t = threadIdx.x, lane = t & 63, wid = t >> 6;
  int n0 = blockIdx.x * NTILE;
  int m0, cnt = 0, off = 0;
  const u16* B16 = (const u16*)Bv;
  const float* B32 = (const float*)Bv;
  const float* bb = bias;
  if (MOE){
    int e = blockIdx.y / mbPerE, mb = blockIdx.y - e * mbPerE;
    cnt = counts[e]; m0 = mb * MTILE;
    if (m0 >= cnt) return;
    off = offsets[e];
    if (BF16B) B16 += (long)e * bSB; else B32 += (long)e * bSB;
    bb += (long)e * biasE;
  } else {
    m0 = blockIdx.y * MTILE;
  }

  long aoff[AF];
#pragma unroll
  for (int i = 0; i < AF; i++){
    int idx = i * 256 + t, c = idx / MTILE, r = idx % MTILE;
    int gl = m0 + r;
    long row;
    if (MOE) row = (gl < cnt) ? (GATHER ? (long)ptok[off + gl] : (long)(off + gl))
                              : (GATHER ? (long)ptok[off] : (long)off);
    else     row = (gl < M) ? gl : 0;
    aoff[i] = row * (long)lda + c * 8;
  }
  long boff[BFN];
#pragma unroll
  for (int i = 0; i < BFN; i++) boff[i] = 0;
  int bcol = 0, bkh = 0;
  const float* b32p = nullptr;
  if (BF16B){
#pragma unroll
    for (int i = 0; i < BFN; i++){
      int idx = i * 256 + t, c = idx / NTILE, r = idx % NTILE;
      int gc = n0 + r; if (gc >= N) gc = 0;
      boff[i] = (long)gc * ldb + c * 8;
    }
  } else {
    if (NTILE == 128){ bcol = t >> 1; bkh = (t & 1) << 4; }
    else             { bcol = t >> 2; bkh = (t & 3) << 3; }
    int gc = n0 + bcol; if (gc >= N) gc = N - 1;
    b32p = B32 + (long)gc * ldb + bkh;
  }

  float4 br[BR];
  auto stage = [&](int buf, int k0){
#pragma unroll
    for (int i = 0; i < AF; i++)
      gload16(A + aoff[i] + k0, &lsa[buf][(i * 256 + wid * 64) * 8]);
    if (BF16B){
#pragma unroll
      for (int i = 0; i < BFN; i++)
        gload16(B16 + boff[i] + k0, &lsb[buf][(i * 256 + wid * 64) * 8]);
    } else {
#pragma unroll
      for (int j = 0; j < BR; j++) br[j] = *(const float4*)(b32p + k0 + j * 4);
    }
  };
  auto bwrite = [&](int buf){
    if (!BF16B){
      if (NTILE == 128){
        bf16x8 w0, w1;
        pack8(br[0], br[1], w0); pack8(br[2], br[3], w1);
        int c0 = bkh >> 3;
        *(bf16x8*)&lsb[buf][((c0    ) * 128 + bcol) * 8] = w0;
        *(bf16x8*)&lsb[buf][((c0 + 1) * 128 + bcol) * 8] = w1;
      } else {
        bf16x8 w0;
        pack8(br[0], br[1], w0);
        *(bf16x8*)&lsb[buf][((bkh >> 3) * 64 + bcol) * 8] = w0;
      }
    }
  };

  f32x4 acc[MF][NF2];
#pragma unroll
  for (int m = 0; m < MF; m++)
#pragma unroll
    for (int n = 0; n < NF2; n++) acc[m][n] = (f32x4){0.f,0.f,0.f,0.f};

  int T = K >> 5;
  stage(0, 0);
  bwrite(0);
  __syncthreads();

  int wr = wid >> 1, wc = wid & 1, fr = lane & 15, lk = lane >> 4;
  for (int tt = 0; tt < T; tt++){
    int cur = tt & 1, nxt = cur ^ 1;
    if (tt + 1 < T) stage(nxt, (tt + 1) << 5);
    bf16x8 av[MF], bv[NF2];
#pragma unroll
    for (int m = 0; m < MF; m++)
      av[m] = *(const bf16x8*)&lsa[cur][(lk * MTILE + wr * (MTILE / 2) + m * 16 + fr) * 8];
#pragma unroll
    for (int n = 0; n < NF2; n++)
      bv[n] = *(const bf16x8*)&lsb[cur][(lk * NTILE + wc * (NTILE / 2) + n * 16 + fr) * 8];
#pragma unroll
    for (int m = 0; m < MF; m++)
#pragma unroll
      for (int n = 0; n < NF2; n++)
        acc[m][n] = __builtin_amdgcn_mfma_f32_16x16x32_bf16(av[m], bv[n], acc[m][n], 0, 0, 0);
    if (tt + 1 < T) bwrite(nxt);
    __syncthreads();
  }

#pragma unroll
  for (int m = 0; m < MF; m++)
#pragma unroll
  for (int i = 0; i < 4; i++){
    int rl = m0 + wr * (MTILE / 2) + m * 16 + lk * 4 + i;
    bool ok = MOE ? (rl < cnt) : (rl < M);
    if (!ok) continue;
    long grow = MOE ? (long)(off + rl) : (long)rl;
    int pph = 0, ppw = 0, pty = 0;
    if (POSTYPE){
      int pb = rl / NV;
      int pid = ids[pb * NP + rl % NV];
      pph = pid / 14; ppw = pid % 14;
      pty = type_ids[pb];
    }
#pragma unroll
    for (int n = 0; n < NF2; n++){
      int col = n0 + wc * (NTILE / 2) + n * 16 + fr;
      if (col >= N) continue;
      float v = acc[m][n][i] + bb[col];
      if (act) v = 0.5f * v * (1.0f + erff(v * 0.70710678118654752f));
      if (POSTYPE){
        int q = col % 192, sect = col / 192;
        float omega = powf(10000.0f, -(float)q / 192.0f);
        float arg = (sect < 2 ? (float)ppw : (float)pph) * omega;
        float pos = ((sect & 1) == 0) ? sinf(arg) : cosf(arg);
        v += pos + type_emb[(long)pty * Dm + col];
      }
      if (Cf) Cf[grow * (long)ldc + col] = v;
      if (Cb) Cb[grow * (long)ldc + col] = f2bf(v);
    }
  }
}

// ---------------- fused flash attention, q-tile 64 ----------------
template<int KVCAP>
__global__ __launch_bounds__(256) void flash_k(
    const u16* __restrict__ Qp, int ldq, int qBatchRows,
    const u16* __restrict__ Kp, int ldk,
    const u16* __restrict__ Vp, int ldv, int kvBatchRows,
    int qCol0, int kCol0, int vCol0,
    int kvLen, u16* __restrict__ Ob)
{
  constexpr int NF   = KVCAP / 16;
  constexpr int HALF = (KVCAP > 128) ? 128 : KVCAP;
  constexpr int NHF  = KVCAP / HALF;

  __shared__ __align__(16) char sm[49152];
  short* smQ  = (short*)sm;
  short* smK0 = (short*)(sm + 12288);
  short* smK1 = (short*)(sm + 12288 + 4 * KVCAP * 16);
  short* smP  = (short*)sm;
  short* smVT = (short*)(sm + 64 * HALF * 2);

  int t = threadIdx.x, lane = t & 63, wid = t >> 6;
  int fr = lane & 15, lk = lane >> 4;
  int qt = blockIdx.x, z = blockIdx.y, b = z >> 3, h = z & 7;
  int qRow0 = b * qBatchRows + qt * 64;
  int kvRow0 = b * kvBatchRows;
  int oRow0 = b * 256 + qt * 64;
  int qCol = qCol0 + h * 96, kCol = kCol0 + h * 96, vCol = vCol0 + h * 96;
  int wq0 = wid * 16;

#pragma unroll
  for (int i = 0; i < 3; i++){
    int idx = i * 256 + t, c = idx >> 6, r = idx & 63;
    *(bf16x8*)&smQ[idx * 8] = *(const bf16x8*)&Qp[(long)(qRow0 + r) * ldq + qCol + c * 8];
  }
  auto stageK = [&](int k0c, short* dst){
#pragma unroll
    for (int i = 0; i < (4 * KVCAP) / 256; i++){
      int idx = i * 256 + t, c = idx / KVCAP, col = idx % KVCAP;
      int kv = col < kvLen ? col : kvLen - 1;
      *(bf16x8*)&dst[idx * 8] =
        *(const bf16x8*)&Kp[(long)(kvRow0 + kv) * ldk + kCol + (k0c * 4 + c) * 8];
    }
  };
  stageK(0, smK0);
  __syncthreads();

  f32x4 acc[NF];
#pragma unroll
  for (int n = 0; n < NF; n++) acc[n] = (f32x4){0.f,0.f,0.f,0.f};

  for (int k0c = 0; k0c < 3; k0c++){
    short* curK = (k0c & 1) ? smK1 : smK0;
    if (k0c < 2) stageK(k0c + 1, (k0c & 1) ? smK0 : smK1);
    bf16x8 av = *(const bf16x8*)&smQ[((k0c * 4 + lk) * 64 + wq0 + fr) * 8];
#pragma unroll
    for (int n = 0; n < NF; n++){
      bf16x8 bv = *(const bf16x8*)&curK[(lk * KVCAP + n * 16 + fr) * 8];
      acc[n] = __builtin_amdgcn_mfma_f32_16x16x32_bf16(av, bv, acc[n], 0, 0, 0);
    }
    __syncthreads();
  }

  const float scl = 0.10206207261596577f;   // 1/sqrt(96)
  float rinv[4];
#pragma unroll
  for (int i = 0; i < 4; i++){
    float mx = -3e38f;
#pragma unroll
    for (int n = 0; n < NF; n++){
      float v = acc[n][i] * scl;
      if (n * 16 + fr >= kvLen) v = -3e38f;
      acc[n][i] = v;
      mx = fmaxf(mx, v);
    }
#pragma unroll
    for (int s = 1; s < 16; s <<= 1) mx = fmaxf(mx, __shfl_xor(mx, s));
    float sum = 0.f;
#pragma unroll
    for (int n = 0; n < NF; n++){
      float p = __expf(acc[n][i] - mx);
      acc[n][i] = p;
      sum += p;
    }
#pragma unroll
    for (int s = 1; s < 16; s <<= 1) sum += __shfl_xor(sum, s);
    rinv[i] = 1.0f / sum;
  }

  f32x4 acco[6];
#pragma unroll
  for (int n = 0; n < 6; n++) acco[n] = (f32x4){0.f,0.f,0.f,0.f};

  for (int hf = 0; hf < NHF; hf++){
    if (hf) __syncthreads();
#pragma unroll
    for (int np = 0; np < HALF / 16; np++){
      int n = hf * (HALF / 16) + np;
#pragma unroll
      for (int i = 0; i < 4; i++){
        int row = wq0 + lk * 4 + i;
        int cl = np * 16 + fr;
        smP[((cl >> 3) * 64 + row) * 8 + (cl & 7)] = (short)f2bf(acc[n][i]);
      }
    }
    constexpr int G = (HALF * 96 / 8) / 256;
#pragma unroll
    for (int g = 0; g < G; g++){
      int flat = g * 256 + t;
      int kvl = flat / 12, dblk = (flat % 12) * 8;
      int kvg = hf * HALF + kvl;
      int kva = kvg < kvLen ? kvg : kvLen - 1;
      bf16x8 v = *(const bf16x8*)&Vp[(long)(kvRow0 + kva) * ldv + vCol + dblk];
      bool zz = kvg >= kvLen;
#pragma unroll
      for (int j = 0; j < 8; j++)
        smVT[((kvl >> 3) * 96 + dblk + j) * 8 + (kvl & 7)] = zz ? (short)0 : v[j];
    }
    __syncthreads();
#pragma unroll
    for (int kk = 0; kk < HALF / 32; kk++){
      bf16x8 pa = *(const bf16x8*)&smP[((kk * 4 + lk) * 64 + wq0 + fr) * 8];
#pragma unroll
      for (int n = 0; n < 6; n++){
        bf16x8 bv = *(const bf16x8*)&smVT[((kk * 4 + lk) * 96 + n * 16 + fr) * 8];
        acco[n] = __builtin_amdgcn_mfma_f32_16x16x32_bf16(pa, bv, acco[n], 0, 0, 0);
      }
    }
  }

#pragma unroll
  for (int n = 0; n < 6; n++)
#pragma unroll
  for (int i = 0; i < 4; i++){
    int row = oRow0 + wq0 + lk * 4 + i;
    Ob[(long)row * 768 + h * 96 + n * 16 + fr] = f2bf(acco[n][i] * rinv[i]);
  }
}

// ---------------- add residual + LN (dual output) ----------------
__global__ __launch_bounds__(256) void add_ln_k(
    const float* __restrict__ X, const float* __restrict__ R, int rMod,
    const float* __restrict__ w, const float* __restrict__ b,
    float* __restrict__ outf, u16* __restrict__ outb)
{
  int row = blockIdx.x;
  int rrow = rMod ? (row % rMod) : row;
  __shared__ float sh[4];
  float x[3];
#pragma unroll
  for (int i = 0; i < 3; i++){
    int d = threadIdx.x + (i << 8);
    x[i] = X[(long)row * Dm + d] + R[(long)rrow * Dm + d];
  }
  float s = blk_sum(x[0] + x[1] + x[2], sh);
  float mean = s * (1.0f / 768.0f);
  float vs = 0.f;
#pragma unroll
  for (int i = 0; i < 3; i++){ float t = x[i] - mean; vs += t * t; }
  vs = blk_sum(vs, sh);
  float rstd = rsqrtf(vs * (1.0f / 768.0f) + 1e-5f);
#pragma unroll
  for (int i = 0; i < 3; i++){
    int d = threadIdx.x + (i << 8);
    float o = (x[i] - mean) * rstd * w[d] + b[d];
    outf[(long)row * Dm + d] = o;
    if (outb) outb[(long)row * Dm + d] = f2bf(o);
  }
}

// ---------------- MoE router ----------------
__global__ __launch_bounds__(256) void router_k(
    const float* __restrict__ lat, const float* __restrict__ rw, const float* __restrict__ rb,
    int* __restrict__ top_idx, float* __restrict__ top_w)
{
  int t = blockIdx.x, tid = threadIdx.x;
  int e = tid >> 5, lane = tid & 31;
  const float* x = lat + (long)t * Dm;
  const float* w = rw + (long)e * Dm;
  float s = 0.f;
  for (int j = 0; j < 24; j++){ int d = lane + 32 * j; s += x[d] * w[d]; }
#pragma unroll
  for (int off = 16; off; off >>= 1) s += __shfl_xor(s, off);
  __shared__ float lg[NE];
  if (lane == 0) lg[e] = s + rb[e];
  __syncthreads();
  if (tid == 0){
    float m = -1e30f;
    for (int i = 0; i < NE; i++) m = fmaxf(m, lg[i]);
    float p[NE]; float se = 0.f;
    for (int i = 0; i < NE; i++){ p[i] = __expf(lg[i] - m); se += p[i]; }
    float inv = 1.0f / se;
    int i0 = 0, i1 = -1; float v0 = -1.f, v1 = -1.f;
    for (int i = 0; i < NE; i++){
      float pi = p[i] * inv;
      if (pi > v0){ v1 = v0; i1 = i0; v0 = pi; i0 = i; }
      else if (pi > v1){ v1 = pi; i1 = i; }
    }
    float w0 = 1.0f / (1.0f + __expf(v1 - v0));
    top_idx[2 * t] = i0; top_idx[2 * t + 1] = i1;
    top_w[2 * t] = w0;   top_w[2 * t + 1] = 1.0f - w0;
  }
}

// ---------------- group token-expert pairs ----------------
__global__ __launch_bounds__(256) void scatter_k(
    const int* __restrict__ top_idx, int* __restrict__ counts, int* __restrict__ offsets,
    int* __restrict__ ptok, int* __restrict__ posmap)
{
  __shared__ int cnt[NE], cur[NE];
  int tid = threadIdx.x;
  if (tid < NE) cnt[tid] = 0;
  __syncthreads();
  for (int t = tid; t < NT; t += 256){
    atomicAdd(&cnt[top_idx[2 * t]], 1);
    atomicAdd(&cnt[top_idx[2 * t + 1]], 1);
  }
  __syncthreads();
  if (tid == 0){
    int o = 0;
    for (int e = 0; e < NE; e++){ offsets[e] = o; cur[e] = o; counts[e] = cnt[e]; o += cnt[e]; }
  }
  __syncthreads();
  for (int t = tid; t < NT; t += 256){
#pragma unroll
    for (int sidx = 0; sidx < 2; sidx++){
      int e = top_idx[2 * t + sidx];
      int pos = atomicAdd(&cur[e], 1);
      ptok[pos] = t;
      posmap[2 * t + sidx] = pos;
    }
  }
}

// ---------------- MoE combine + residual + LN ----------------
__global__ __launch_bounds__(256) void moe_combine_ln_k(
    const float* __restrict__ OBuf, const int* __restrict__ posmap, const float* __restrict__ topw,
    const float* __restrict__ latin, const float* __restrict__ w, const float* __restrict__ b,
    float* __restrict__ outf, u16* __restrict__ outb)
{
  int t = blockIdx.x;
  int p0 = posmap[2 * t], p1 = posmap[2 * t + 1];
  float w0 = topw[2 * t], w1 = topw[2 * t + 1];
  __shared__ float sh[4];
  float x[3];
#pragma unroll
  for (int i = 0; i < 3; i++){
    int d = threadIdx.x + (i << 8);
    x[i] = w0 * OBuf[(long)p0 * Dm + d] + w1 * OBuf[(long)p1 * Dm + d] + latin[(long)t * Dm + d];
  }
  float s = blk_sum(x[0] + x[1] + x[2], sh);
  float mean = s * (1.0f / 768.0f);
  float vs = 0.f;
#pragma unroll
  for (int i = 0; i < 3; i++){ float tt = x[i] - mean; vs += tt * tt; }
  vs = blk_sum(vs, sh);
  float rstd = rsqrtf(vs * (1.0f / 768.0f) + 1e-5f);
#pragma unroll
  for (int i = 0; i < 3; i++){
    int d = threadIdx.x + (i << 8);
    float o = (x[i] - mean) * rstd * w[d] + b[d];
    outf[(long)t * Dm + d] = o;
    if (outb) outb[(long)t * Dm + d] = f2bf(o);
  }
}

} // namespace

extern "C" void kernel_launch(void* const* d_in, const int* in_sizes, int n_in,
                              void* d_out, int out_size, void* d_ws, size_t ws_size,
                              hipStream_t stream)
{
  (void)in_sizes; (void)n_in; (void)out_size; (void)ws_size;
  const float* images    = (const float*)d_in[0];
  const int*   type_ids  = (const int*)d_in[1];
  const float* noise     = (const float*)d_in[2];
  const float* conv_w    = (const float*)d_in[3];
  const float* conv_b    = (const float*)d_in[4];
  const float* latents   = (const float*)d_in[5];
  const float* type_emb  = (const float*)d_in[6];
  const float* ca_in_w   = (const float*)d_in[7];
  const float* ca_in_b   = (const float*)d_in[8];
  const float* ca_out_w  = (const float*)d_in[9];
  const float* ca_out_b  = (const float*)d_in[10];
  const float* ca_ln_w   = (const float*)d_in[11];
  const float* ca_ln_b   = (const float*)d_in[12];
  const float* blk_in_w  = (const float*)d_in[13];
  const float* blk_in_b  = (const float*)d_in[14];
  const float* blk_out_w = (const float*)d_in[15];
  const float* blk_out_b = (const float*)d_in[16];
  const float* blk_ln1_w = (const float*)d_in[17];
  const float* blk_ln1_b = (const float*)d_in[18];
  const float* blk_ln2_w = (const float*)d_in[19];
  const float* blk_ln2_b = (const float*)d_in[20];
  const float* router_w  = (const float*)d_in[21];
  const float* router_b  = (const float*)d_in[22];
  const float* e_w1      = (const float*)d_in[23];
  const float* e_b1      = (const float*)d_in[24];
  const float* e_w2      = (const float*)d_in[25];
  const float* e_b2      = (const float*)d_in[26];

  char* W = (char*)d_ws;
  float* lat   = (float*)(W + 0);              // 3,145,728
  float* tmp   = (float*)(W + 3145728);        // 3,145,728
  float* obuf  = (float*)(W + 6291456);        // 6,291,456
  float* topw  = (float*)(W + 13185024);
  int*   ids      = (int*)(W + 13193216);
  int*   top_idx  = (int*)(W + 13197312);
  int*   posmap   = (int*)(W + 13205504);
  int*   ptok     = (int*)(W + 13213696);
  int*   counts   = (int*)(W + 13221888);
  int*   offsets  = (int*)(W + 13221952);
  u16* lat_bf    = (u16*)(W + 13258752);       // 1,572,864
  u16* ao_bf     = (u16*)(W + 14831616);       // 1,572,864
  u16* qkv_bf    = (u16*)(W + 16404480);       // 4,718,592
  u16* h_bf      = (u16*)(W + 21123072);       // 6,291,456
  u16* viscol_bf = (u16*)(W + 27414528);       //   301,056
  u16* vis_bf    = (u16*)(W + 27715584);       //   301,056
  u16* qq_bf     = (u16*)(W + 28016640);       //   393,216
  u16* kkvv_bf   = (u16*)(W + 28409856);       //   602,112
  u16* lat0_bf   = (u16*)(W + 29011968);       //   393,216
  u16* convw_bf  = (u16*)(W + 29405184);       // 1,179,648
  u16* caw_bf    = (u16*)(W + 30584832);       // 3,538,944
  u16* caow_bf   = (u16*)(W + 34123776);       // 1,179,648
  u16* blkin_bf  = (u16*)(W + 35303424);       // 21,233,664
  u16* blkout_bf = (u16*)(W + 56537088);       // 7,077,888

  float* out      = (float*)d_out;
  float* out_lat  = out;
  float* out_keep = out + (long)NT * Dm;
  float* out_mask = out_keep + BB * NV;

  dim3 blk(256);

  // ---- merged prologue: argsort + im2col + weight cvt ----
  prologue_k<<<2248, blk, 0, stream>>>(
      noise, ids, out_keep, out_mask, images, viscol_bf,
      conv_w, ca_in_w, ca_out_w, blk_in_w, blk_out_w, latents,
      convw_bf, caw_bf, caow_bf, blkin_bf, blkout_bf, lat0_bf);

  // ---- conv GEMM with fused pos+type epilogue ----
  g2_k<64,64,true,false,false,true><<<dim3(12, 4), blk, 0, stream>>>(
      viscol_bf, Dm, convw_bf, Dm, 0, conv_b, 0,
      nullptr, vis_bf, Dm, BB * NV, Dm, Dm, 0,
      nullptr, nullptr, nullptr, 1, ids, type_ids, type_emb);

  // ---- cross attention ----
  g2_k<64,64,true,false,false,false><<<dim3(12, 4), blk, 0, stream>>>(
      lat0_bf, Dm, caw_bf, Dm, 0, ca_in_b, 0,
      nullptr, qq_bf, Dm, ML, Dm, Dm, 0,
      nullptr, nullptr, nullptr, 1, nullptr, nullptr, nullptr);
  g2_k<64,64,true,false,false,false><<<dim3(24, 4), blk, 0, stream>>>(
      vis_bf, Dm, caw_bf + 768 * 768, Dm, 0, ca_in_b + 768, 0,
      nullptr, kkvv_bf, 1536, BB * NV, 1536, Dm, 0,
      nullptr, nullptr, nullptr, 1, nullptr, nullptr, nullptr);
  flash_k<64><<<dim3(4, 32), blk, 0, stream>>>(
      qq_bf, Dm, 0, kkvv_bf, 1536, kkvv_bf, 1536, NV, 0, 0, 768, NV, ao_bf);
  g2_k<64,64,true,false,false,false><<<dim3(12, 16), blk, 0, stream>>>(
      ao_bf, Dm, caow_bf, Dm, 0, ca_out_b, 0,
      tmp, nullptr, Dm, NT, Dm, Dm, 0,
      nullptr, nullptr, nullptr, 1, nullptr, nullptr, nullptr);
  add_ln_k<<<NT, blk, 0, stream>>>(tmp, latents, ML, ca_ln_w, ca_ln_b, lat, lat_bf);

  // ---- transformer blocks ----
  for (int l = 0; l < NL; l++){
    g2_k<64,64,true,false,false,false><<<dim3(36, 16), blk, 0, stream>>>(
        lat_bf, Dm, blkin_bf + (long)l * 2304 * 768, Dm, 0, blk_in_b + (long)l * 2304, 0,
        nullptr, qkv_bf, 2304, NT, 2304, Dm, 0,
        nullptr, nullptr, nullptr, 1, nullptr, nullptr, nullptr);
    flash_k<256><<<dim3(4, 32), blk, 0, stream>>>(
        qkv_bf, 2304, ML, qkv_bf, 2304, qkv_bf, 2304, ML, 0, 768, 1536, ML, ao_bf);
    g2_k<64,64,true,false,false,false><<<dim3(12, 16), blk, 0, stream>>>(
        ao_bf, Dm, blkout_bf + (long)l * 768 * 768, Dm, 0, blk_out_b + (long)l * 768, 0,
        tmp, nullptr, Dm, NT, Dm, Dm, 0,
        nullptr, nullptr, nullptr, 1, nullptr, nullptr, nullptr);
    add_ln_k<<<NT, blk, 0, stream>>>(tmp, lat, 0,
        blk_ln1_w + (long)l * 768, blk_ln1_b + (long)l * 768, lat, lat_bf);
    router_k<<<NT, blk, 0, stream>>>(lat, router_w + (long)l * NE * Dm,
                                     router_b + (long)l * NE, top_idx, topw);
    scatter_k<<<1, blk, 0, stream>>>(top_idx, counts, offsets, ptok, posmap);
    g2_k<64,64,false,true,true,false><<<dim3(24, 128), blk, 0, stream>>>(
        lat_bf, Dm, e_w1 + (long)l * NE * FH_ * Dm, Dm, (long)FH_ * Dm,
        e_b1 + (long)l * NE * FH_, FH_,
        nullptr, h_bf, FH_, 0, FH_, Dm, 1,
        counts, offsets, ptok, 16, nullptr, nullptr, nullptr);
    g2_k<64,64,false,true,false,false><<<dim3(12, 128), blk, 0, stream>>>(
        h_bf, FH_, e_w2 + (long)l * NE * Dm * FH_, FH_, (long)Dm * FH_,
        e_b2 + (long)l * NE * Dm, Dm,
        obuf, nullptr, Dm, 0, Dm, FH_, 0,
        counts, offsets, ptok, 16, nullptr, nullptr, nullptr);
    moe_combine_ln_k<<<NT, blk, 0, stream>>>(obuf, posmap, topw, lat,
        blk_ln2_w + (long)l * 768, blk_ln2_b + (long)l * 768,
        (l == NL - 1) ? out_lat : lat, (l == NL - 1) ? nullptr : lat_bf);
  }
}